// Round 9
// baseline (37.542 us; speedup 1.0000x reference)
//
#include <hip/hip_runtime.h>
#include <hip/hip_bf16.h>

#define F_IN 128
#define F_OUT 64

typedef __attribute__((ext_vector_type(8))) short short8;
typedef __attribute__((ext_vector_type(4))) float f32x4;

__device__ __forceinline__ unsigned short f2bf_rne(float f) {
  unsigned int u = __builtin_bit_cast(unsigned int, f);
  u += 0x7fffu + ((u >> 16) & 1u);
  return (unsigned short)(u >> 16);
}
__device__ __forceinline__ float bfu2f(unsigned short u) {
  return __builtin_bit_cast(float, (unsigned int)u << 16);
}

// ---------------------------------------------------------------------------
// Kernel A (fused): blocks [0, gemm_blocks): pre8 = int8_rowscaled(x @ W),
// scales[r] = rowmax/127; blocks [gemm_blocks, ..): row_ptr binary search.
//
// GEMM: wave -> 16-row m-tile; W^T staged as bf16 hi+lo in 32 KB LDS
// (XOR-swizzled); x split hi/lo on the fly. acc = ah*bh + al*bh + ah*bl
// (R3-measured base absmax 0.25). Epilogue: per-row absmax via 4x shfl_xor
// within the 16-lane row group, quantize to int8, pack 4 features/uint.
// Byte layout: pre8[row*64 + fl*4 + j] = feature j*16+fl  (so both this
// store and the spmm's decode/store are coalesced).
// ---------------------------------------------------------------------------
__global__ __launch_bounds__(256) void gcn_gemm_rowptr(
    const float* __restrict__ x, const float* __restrict__ w,
    signed char* __restrict__ pre8, float* __restrict__ scales,
    const int* __restrict__ edge_row, int* __restrict__ row_ptr,
    int n_nodes, int n_edges, int gemm_blocks) {
  const int tid = threadIdx.x;

  if (blockIdx.x >= gemm_blocks) {  // ---- rowptr path ----
    const int r = (blockIdx.x - gemm_blocks) * 256 + tid;
    if (r > n_nodes) return;
    int lo = 0, hi = n_edges;
    while (lo < hi) {
      const int mid = (lo + hi) >> 1;
      if (edge_row[mid] < r) lo = mid + 1; else hi = mid;
    }
    row_ptr[r] = lo;
    return;
  }

  // ---- GEMM path ----
  __shared__ __align__(16) unsigned short wt_hi[64 * 128];  // 16 KB
  __shared__ __align__(16) unsigned short wt_lo[64 * 128];  // 16 KB

  {  // stage W^T hi/lo: coalesced float4 reads, scatter u16 into LDS
#pragma unroll
    for (int i = 0; i < 8; ++i) {
      const int flat4 = tid + i * 256;
      const float4 v = ((const float4*)w)[flat4];
      const float fv[4] = {v.x, v.y, v.z, v.w};
#pragma unroll
      for (int j = 0; j < 4; ++j) {
        const int flat = flat4 * 4 + j;          // flat = k*64 + n
        const int k = flat >> 6;
        const int n = flat & 63;
        int off = (n << 8) + (k << 1);
        off ^= (n & 7) << 4;
        const unsigned short h = f2bf_rne(fv[j]);
        *(unsigned short*)((char*)wt_hi + off) = h;
        *(unsigned short*)((char*)wt_lo + off) = f2bf_rne(fv[j] - bfu2f(h));
      }
    }
  }
  __syncthreads();

  const int lane = tid & 63;
  const int mt = blockIdx.x * 4 + (tid >> 6);
  const int m0 = mt * 16;
  if (m0 >= n_nodes) return;

  const int lrow = lane & 15;
  const int lk = lane >> 4;
  const bool full = (m0 + 16 <= n_nodes);
  const int arow = full ? (m0 + lrow) : min(m0 + lrow, n_nodes - 1);

  f32x4 acc[4];
#pragma unroll
  for (int i = 0; i < 4; ++i) acc[i] = (f32x4){0.f, 0.f, 0.f, 0.f};

#pragma unroll
  for (int ks = 0; ks < 4; ++ks) {
    const float4* xp =
        (const float4*)(x + (size_t)arow * F_IN + ks * 32 + lk * 8);
    const float4 q0 = xp[0];
    const float4 q1 = xp[1];
    const float fv[8] = {q0.x, q0.y, q0.z, q0.w, q1.x, q1.y, q1.z, q1.w};
    short8 ah, al;
#pragma unroll
    for (int i = 0; i < 8; ++i) {
      const unsigned short h = f2bf_rne(fv[i]);
      ah[i] = (short)h;
      al[i] = (short)f2bf_rne(fv[i] - bfu2f(h));
    }
#pragma unroll
    for (int nt = 0; nt < 4; ++nt) {
      const int n = nt * 16 + lrow;
      int off = (n << 8) + (ks * 64 + lk * 16);
      off ^= (n & 7) << 4;
      const short8 bh = *(const short8*)((const char*)wt_hi + off);
      const short8 bl = *(const short8*)((const char*)wt_lo + off);
      acc[nt] = __builtin_amdgcn_mfma_f32_16x16x32_bf16(ah, bh, acc[nt], 0, 0, 0);
      acc[nt] = __builtin_amdgcn_mfma_f32_16x16x32_bf16(al, bh, acc[nt], 0, 0, 0);
      acc[nt] = __builtin_amdgcn_mfma_f32_16x16x32_bf16(ah, bl, acc[nt], 0, 0, 0);
    }
  }

  // C/D: col = lane&15 (= lrow), row-in-tile = lk*4 + reg  [HW-verified]
  // Row (lk,r) lives across the 16 lanes lk*16+0..15 -> shfl_xor{1,2,4,8}.
#pragma unroll
  for (int r = 0; r < 4; ++r) {
    float m = fmaxf(fmaxf(fabsf(acc[0][r]), fabsf(acc[1][r])),
                    fmaxf(fabsf(acc[2][r]), fabsf(acc[3][r])));
    m = fmaxf(m, __shfl_xor(m, 1));
    m = fmaxf(m, __shfl_xor(m, 2));
    m = fmaxf(m, __shfl_xor(m, 4));
    m = fmaxf(m, __shfl_xor(m, 8));
    const float iv = m > 0.f ? 127.0f / m : 0.f;
    const int row = m0 + lk * 4 + r;
    if (full || row < n_nodes) {
      const int q0 = __float2int_rn(acc[0][r] * iv);
      const int q1 = __float2int_rn(acc[1][r] * iv);
      const int q2 = __float2int_rn(acc[2][r] * iv);
      const int q3 = __float2int_rn(acc[3][r] * iv);
      const unsigned int u = (q0 & 0xff) | ((q1 & 0xff) << 8) |
                             ((q2 & 0xff) << 16) | ((unsigned)(q3 & 0xff) << 24);
      *(unsigned int*)(pre8 + (size_t)row * 64 + lrow * 4) = u;
      if (lrow == 0) scales[row] = m * (1.0f / 127.0f);
    }
  }
}

// ---------------------------------------------------------------------------
// Kernel B: out[r][f] = relu( sum_e val[e]*scales[col[e]] * q8[col[e]][f] )
// FOUR ROWS PER WAVE; quarter q owns row rbase+q. Lane (q,fl) gathers one
// uint = 4 int8 (features {fl,16+fl,32+fl,48+fl}); one gather instruction
// serves 4 edges (4 x 64 B segments). pre8 is 3.2 MB -> L2-resident after
// compulsory fill. Scale folded into edge weight at metadata preload.
// Per 16-step batch: coalesced meta preload + s-gather, 32 bpermute
// broadcasts, 16 independent gathers, 64 decode+fma. Padded slots: v=0,
// row-0 gather (L2-hot). No cross-lane reduce; 4 coalesced 256-B stores.
// Fixed order -> deterministic.
// ---------------------------------------------------------------------------
__global__ __launch_bounds__(256) void gcn_spmm(
    const signed char* __restrict__ pre8, const float* __restrict__ scales,
    const int* __restrict__ row_ptr, const int* __restrict__ edge_col,
    const float* __restrict__ edge_val, float* __restrict__ out, int n_nodes) {
  const int lane = threadIdx.x & 63;
  const int q  = lane >> 4;   // quarter -> owns row rbase+q
  const int fl = lane & 15;   // uint index within the 64-B row
  const int wid = (int)((blockIdx.x * blockDim.x + threadIdx.x) >> 6);
  const int rbase = wid * 4;
  if (rbase >= n_nodes) return;

  const int myrow = rbase + q;
  const bool valid = myrow < n_nodes;
  const int rowc = valid ? myrow : n_nodes - 1;
  const int e0 = row_ptr[rowc];
  const int e1 = valid ? row_ptr[rowc + 1] : e0;

  int md = e1 - e0;
  md = max(md, __shfl_xor(md, 16));
  md = max(md, __shfl_xor(md, 32));

  float a0 = 0.f, a1 = 0.f, a2 = 0.f, a3 = 0.f;
  const char* pb = (const char*)pre8 + (fl << 2);

  for (int sb = 0; sb < md; sb += 16) {
    // preload: lane (q,fl) holds edge e0q + sb + fl, weight pre-scaled
    int myc = 0;
    float myv = 0.f;
    const int ei = e0 + sb + fl;
    if (ei < e1) {
      const int c = edge_col[ei];
      myv = edge_val[ei] * scales[c];
      myc = c << 6;  // byte offset of the 64-B int8 row
    }
    const int qb = lane & 48;  // q*16
    int   cc[16];
    float vv[16];
#pragma unroll
    for (int j = 0; j < 16; ++j) {
      cc[j] = __shfl(myc, qb + j);
      vv[j] = __shfl(myv, qb + j);
    }
    unsigned int p[16];
#pragma unroll
    for (int j = 0; j < 16; ++j)
      p[j] = *(const unsigned int*)(pb + (size_t)(unsigned int)cc[j]);
#pragma unroll
    for (int j = 0; j < 16; ++j) {
      a0 = fmaf(vv[j], (float)((int)(p[j] << 24) >> 24), a0);
      a1 = fmaf(vv[j], (float)((int)(p[j] << 16) >> 24), a1);
      a2 = fmaf(vv[j], (float)((int)(p[j] <<  8) >> 24), a2);
      a3 = fmaf(vv[j], (float)((int)p[j] >> 24), a3);
    }
  }

  if (valid) {
    float* ob = out + (size_t)myrow * F_OUT + fl;  // feature j*16+fl
    ob[0]  = fmaxf(a0, 0.f);
    ob[16] = fmaxf(a1, 0.f);
    ob[32] = fmaxf(a2, 0.f);
    ob[48] = fmaxf(a3, 0.f);
  }
}

extern "C" void kernel_launch(void* const* d_in, const int* in_sizes, int n_in,
                              void* d_out, int out_size, void* d_ws, size_t ws_size,
                              hipStream_t stream) {
  const float* x        = (const float*)d_in[0];
  const float* w        = (const float*)d_in[1];
  const int*   edge_row = (const int*)d_in[2];
  const int*   edge_col = (const int*)d_in[3];
  const float* edge_val = (const float*)d_in[4];
  float* out = (float*)d_out;

  const int n_nodes = in_sizes[0] / F_IN;   // 50000
  const int n_edges = in_sizes[2];          // 800000

  signed char* pre8 = (signed char*)d_ws;                       // 3.2 MB
  float* scales = (float*)((char*)d_ws + (size_t)n_nodes * 64); // 200 KB
  int* row_ptr  = (int*)((char*)d_ws + (size_t)n_nodes * 64 +
                         (size_t)n_nodes * sizeof(float));      // 200 KB

  const int m_tiles = (n_nodes + 15) / 16;
  const int gemm_blocks = (m_tiles + 3) / 4;
  const int rp_blocks = (n_nodes + 1 + 255) / 256;
  gcn_gemm_rowptr<<<gemm_blocks + rp_blocks, 256, 0, stream>>>(
      x, w, pre8, scales, edge_row, row_ptr, n_nodes, n_edges, gemm_blocks);

  // 4 rows per wave, 4 waves per block -> 16 rows per block
  const int spmm_blocks = (n_nodes + 15) / 16;
  gcn_spmm<<<spmm_blocks, 256, 0, stream>>>(pre8, scales, row_ptr, edge_col,
                                            edge_val, out, n_nodes);
}

// Round 10
// 34.296 us; speedup vs baseline: 1.0946x; 1.0946x over previous
//
#include <hip/hip_runtime.h>
#include <hip/hip_bf16.h>

#define F_IN 128
#define F_OUT 64
#define CHUNK_EDGES 1024  // 8 KB LDS metadata buffer

typedef __attribute__((ext_vector_type(8))) short short8;
typedef __attribute__((ext_vector_type(4))) float f32x4;

__device__ __forceinline__ unsigned short f2bf_rne(float f) {
  unsigned int u = __builtin_bit_cast(unsigned int, f);
  u += 0x7fffu + ((u >> 16) & 1u);
  return (unsigned short)(u >> 16);
}
__device__ __forceinline__ float bf_lo(unsigned int u) {
  return __builtin_bit_cast(float, u << 16);
}
__device__ __forceinline__ float bf_hi(unsigned int u) {
  return __builtin_bit_cast(float, u & 0xffff0000u);
}

// ---------------------------------------------------------------------------
// Kernel A (fused): blocks [0, gemm_blocks) compute pre = bf16(x @ W) via
// MFMA; blocks [gemm_blocks, ..) compute row_ptr by binary search.
// GEMM: wave -> 16-row m-tile; W^T staged bf16 in 16 KB LDS, XOR-swizzled;
// x single-rounded bf16 -> 1 MFMA per (ks, nt). (R6-verified, absmax 1.0.)
// ---------------------------------------------------------------------------
__global__ __launch_bounds__(256) void gcn_gemm_rowptr(
    const float* __restrict__ x, const float* __restrict__ w,
    unsigned short* __restrict__ pre,
    const int* __restrict__ edge_row, int* __restrict__ row_ptr,
    int n_nodes, int n_edges, int gemm_blocks) {
  const int tid = threadIdx.x;

  if (blockIdx.x >= gemm_blocks) {  // ---- rowptr path ----
    const int r = (blockIdx.x - gemm_blocks) * 256 + tid;
    if (r > n_nodes) return;
    int lo = 0, hi = n_edges;
    while (lo < hi) {
      const int mid = (lo + hi) >> 1;
      if (edge_row[mid] < r) lo = mid + 1; else hi = mid;
    }
    row_ptr[r] = lo;
    return;
  }

  // ---- GEMM path ----
  __shared__ __align__(16) unsigned short wt_hi[64 * 128];  // 16 KB

  {  // stage W^T: coalesced float4 reads, convert, scatter u16 into LDS
#pragma unroll
    for (int i = 0; i < 8; ++i) {
      const int flat4 = tid + i * 256;
      const float4 v = ((const float4*)w)[flat4];
      const float fv[4] = {v.x, v.y, v.z, v.w};
#pragma unroll
      for (int j = 0; j < 4; ++j) {
        const int flat = flat4 * 4 + j;          // flat = k*64 + n
        const int k = flat >> 6;
        const int n = flat & 63;
        int off = (n << 8) + (k << 1);
        off ^= (n & 7) << 4;
        *(unsigned short*)((char*)wt_hi + off) = f2bf_rne(fv[j]);
      }
    }
  }
  __syncthreads();

  const int lane = tid & 63;
  const int mt = blockIdx.x * 4 + (tid >> 6);
  const int m0 = mt * 16;
  if (m0 >= n_nodes) return;

  const int lrow = lane & 15;
  const int lk = lane >> 4;
  const bool full = (m0 + 16 <= n_nodes);
  const int arow = full ? (m0 + lrow) : min(m0 + lrow, n_nodes - 1);

  f32x4 acc[4];
#pragma unroll
  for (int i = 0; i < 4; ++i) acc[i] = (f32x4){0.f, 0.f, 0.f, 0.f};

#pragma unroll
  for (int ks = 0; ks < 4; ++ks) {
    const float4* xp =
        (const float4*)(x + (size_t)arow * F_IN + ks * 32 + lk * 8);
    const float4 q0 = xp[0];
    const float4 q1 = xp[1];
    const float fv[8] = {q0.x, q0.y, q0.z, q0.w, q1.x, q1.y, q1.z, q1.w};
    short8 ah;
#pragma unroll
    for (int i = 0; i < 8; ++i) ah[i] = (short)f2bf_rne(fv[i]);
#pragma unroll
    for (int nt = 0; nt < 4; ++nt) {
      const int n = nt * 16 + lrow;
      int off = (n << 8) + (ks * 64 + lk * 16);
      off ^= (n & 7) << 4;
      const short8 bh = *(const short8*)((const char*)wt_hi + off);
      acc[nt] = __builtin_amdgcn_mfma_f32_16x16x32_bf16(ah, bh, acc[nt], 0, 0, 0);
    }
  }

  // C/D: col = lane&15, row = (lane>>4)*4 + reg  [HW-verified]
#pragma unroll
  for (int nt = 0; nt < 4; ++nt) {
#pragma unroll
    for (int r = 0; r < 4; ++r) {
      const int row = m0 + lk * 4 + r;
      if (full || row < n_nodes)
        pre[(size_t)row * F_OUT + nt * 16 + lrow] = f2bf_rne(acc[nt][r]);
    }
  }
}

// ---------------------------------------------------------------------------
// Kernel B: out[r][f] = relu( sum_e val[e] * pre_bf16[col[e]][f] )
// BLOCK-CSR: block owns 16 rows = one contiguous edge range (rows sorted).
// All 256 threads stage the range's (col<<7, val) pairs into LDS ONCE,
// fully coalesced (one VMEM round trip per ~256 edges). Quarter-wave
// (16 lanes) owns one row; per edge it does a quarter-uniform ds_read_b64
// (broadcast, pipelined under gathers by the compiler) + one uint2 gather
// (4 bf16 features) + 4 fma. 8-deep unroll -> 8 independent gathers in
// flight; serial chain per 8 edges = ONE VMEM round trip. Chunk loop
// (1024-edge LDS cap) handles degree outliers. Store: coalesced float4.
// Fixed order -> deterministic.
// ---------------------------------------------------------------------------
__global__ __launch_bounds__(256) void gcn_spmm(
    const unsigned short* __restrict__ pre, const int* __restrict__ row_ptr,
    const int* __restrict__ edge_col, const float* __restrict__ edge_val,
    float* __restrict__ out, int n_nodes) {
  __shared__ uint2 meta[CHUNK_EDGES];  // 8 KB

  const int tid = threadIdx.x;
  const int lane = tid & 63;
  const int wv = tid >> 6;
  const int q = lane >> 4;
  const int fl = lane & 15;
  const int rbase = blockIdx.x * 16;

  const int myrow = rbase + wv * 4 + q;
  const bool valid = myrow < n_nodes;
  const int rowc = valid ? myrow : n_nodes - 1;
  const int my_e0 = row_ptr[rowc];
  const int my_e1 = valid ? row_ptr[rowc + 1] : my_e0;

  const int blk_last = min(rbase + 16, n_nodes);
  const int blk_e0 = row_ptr[rbase];
  const int blk_e1 = row_ptr[blk_last];

  float a0 = 0.f, a1 = 0.f, a2 = 0.f, a3 = 0.f;
  const char* pb = (const char*)pre + ((size_t)fl << 3);  // fl-th uint2

  for (int ch = blk_e0; ch < blk_e1; ch += CHUNK_EDGES) {
    const int cend = min(ch + CHUNK_EDGES, blk_e1);
    const int cnt = cend - ch;
    if (ch != blk_e0) __syncthreads();  // protect LDS reuse (rare path)
    for (int i = tid; i < cnt; i += 256)
      meta[i] = make_uint2((unsigned)edge_col[ch + i] << 7,
                           __float_as_uint(edge_val[ch + i]));
    __syncthreads();

    // my clipped range within this chunk (LDS indices)
    const int s = max(my_e0, ch) - ch;
    const int t = min(my_e1, cend) - ch;

    int j = s;
    for (; j + 8 <= t; j += 8) {
      uint2 m[8];
#pragma unroll
      for (int u = 0; u < 8; ++u) m[u] = meta[j + u];
      uint2 p[8];
#pragma unroll
      for (int u = 0; u < 8; ++u)
        p[u] = *(const uint2*)(pb + (size_t)m[u].x);
#pragma unroll
      for (int u = 0; u < 8; ++u) {
        const float v = __builtin_bit_cast(float, m[u].y);
        a0 = fmaf(v, bf_lo(p[u].x), a0);
        a1 = fmaf(v, bf_hi(p[u].x), a1);
        a2 = fmaf(v, bf_lo(p[u].y), a2);
        a3 = fmaf(v, bf_hi(p[u].y), a3);
      }
    }
    for (; j < t; ++j) {  // tail: < 8 edges
      const uint2 m = meta[j];
      const uint2 p = *(const uint2*)(pb + (size_t)m.x);
      const float v = __builtin_bit_cast(float, m.y);
      a0 = fmaf(v, bf_lo(p.x), a0);
      a1 = fmaf(v, bf_hi(p.x), a1);
      a2 = fmaf(v, bf_lo(p.y), a2);
      a3 = fmaf(v, bf_hi(p.y), a3);
    }
  }

  if (valid) {
    float4 o;
    o.x = fmaxf(a0, 0.f);
    o.y = fmaxf(a1, 0.f);
    o.z = fmaxf(a2, 0.f);
    o.w = fmaxf(a3, 0.f);
    *(float4*)(out + (size_t)myrow * F_OUT + fl * 4) = o;  // 256 B / quarter
  }
}

extern "C" void kernel_launch(void* const* d_in, const int* in_sizes, int n_in,
                              void* d_out, int out_size, void* d_ws, size_t ws_size,
                              hipStream_t stream) {
  const float* x        = (const float*)d_in[0];
  const float* w        = (const float*)d_in[1];
  const int*   edge_row = (const int*)d_in[2];
  const int*   edge_col = (const int*)d_in[3];
  const float* edge_val = (const float*)d_in[4];
  float* out = (float*)d_out;

  const int n_nodes = in_sizes[0] / F_IN;   // 50000
  const int n_edges = in_sizes[2];          // 800000

  unsigned short* pre = (unsigned short*)d_ws;  // n_nodes*64 bf16 = 6.4 MB
  int* row_ptr = (int*)((char*)d_ws +
                        (size_t)n_nodes * F_OUT * sizeof(unsigned short));

  const int m_tiles = (n_nodes + 15) / 16;
  const int gemm_blocks = (m_tiles + 3) / 4;
  const int rp_blocks = (n_nodes + 1 + 255) / 256;
  gcn_gemm_rowptr<<<gemm_blocks + rp_blocks, 256, 0, stream>>>(
      x, w, pre, edge_row, row_ptr, n_nodes, n_edges, gemm_blocks);

  // 16 rows per block (4 waves x 4 quarter-owned rows)
  const int spmm_blocks = (n_nodes + 15) / 16;
  gcn_spmm<<<spmm_blocks, 256, 0, stream>>>(pre, row_ptr, edge_col, edge_val,
                                            out, n_nodes);
}

// Round 11
// 34.160 us; speedup vs baseline: 1.0990x; 1.0040x over previous
//
#include <hip/hip_runtime.h>
#include <hip/hip_bf16.h>

#define F_IN 128
#define F_OUT 64

typedef __attribute__((ext_vector_type(8))) short short8;
typedef __attribute__((ext_vector_type(4))) float f32x4;

__device__ __forceinline__ unsigned short f2bf_rne(float f) {
  unsigned int u = __builtin_bit_cast(unsigned int, f);
  u += 0x7fffu + ((u >> 16) & 1u);
  return (unsigned short)(u >> 16);
}
__device__ __forceinline__ float bf_lo(unsigned int u) {
  return __builtin_bit_cast(float, u << 16);
}
__device__ __forceinline__ float bf_hi(unsigned int u) {
  return __builtin_bit_cast(float, u & 0xffff0000u);
}

// ---------------------------------------------------------------------------
// Kernel A (fused): blocks [0, gemm_blocks) compute pre = bf16(x @ W) via
// MFMA; blocks [gemm_blocks, ..) compute row_ptr by binary search.
//
// W-staging (NEW): transpose happens in the GLOBAL read. Each wave's kc is
// wave-uniform (kc = waveid*32), n = lane -> every global read instruction
// is a contiguous 256 B row of W (perfect coalescing, L2-hot after block 0).
// Each thread packs 8 k's into a short8 and issues 4 ds_write_b128 with the
// (n&7)<<4 XOR swizzle: 64 lanes spread evenly over all 8 bank quads =
// minimum-cycle b128 writes. Replaces 128 conflicted ds_write_b16 wave-ops
// (~16-way, ~2048 LDS cyc/block) with 16 clean b128 wave-ops (~200 cyc).
// Fragment reads + MFMA + epilogue unchanged (R6-verified, absmax 1.0).
// ---------------------------------------------------------------------------
__global__ __launch_bounds__(256) void gcn_gemm_rowptr(
    const float* __restrict__ x, const float* __restrict__ w,
    unsigned short* __restrict__ pre,
    const int* __restrict__ edge_row, int* __restrict__ row_ptr,
    int n_nodes, int n_edges, int gemm_blocks) {
  const int tid = threadIdx.x;

  if (blockIdx.x >= gemm_blocks) {  // ---- rowptr path ----
    const int r = (blockIdx.x - gemm_blocks) * 256 + tid;
    if (r > n_nodes) return;
    int lo = 0, hi = n_edges;
    while (lo < hi) {
      const int mid = (lo + hi) >> 1;
      if (edge_row[mid] < r) lo = mid + 1; else hi = mid;
    }
    row_ptr[r] = lo;
    return;
  }

  // ---- GEMM path ----
  __shared__ __align__(16) unsigned short wt_hi[64 * 128];  // 16 KB

  {  // stage W^T: per-wave-uniform k, lane-contiguous n reads; b128 writes
    const int n  = tid & 63;
    const int kc = (tid >> 6) * 32;  // wave-uniform
#pragma unroll
    for (int j = 0; j < 4; ++j) {
      short8 hv;
#pragma unroll
      for (int i = 0; i < 8; ++i)
        hv[i] = (short)f2bf_rne(w[(kc + j * 8 + i) * F_OUT + n]);
      int off = (n << 8) + ((kc + j * 8) << 1);
      off ^= (n & 7) << 4;
      *(short8*)((char*)wt_hi + off) = hv;
    }
  }
  __syncthreads();

  const int lane = tid & 63;
  const int mt = blockIdx.x * 4 + (tid >> 6);
  const int m0 = mt * 16;
  if (m0 >= n_nodes) return;

  const int lrow = lane & 15;
  const int lk = lane >> 4;
  const bool full = (m0 + 16 <= n_nodes);
  const int arow = full ? (m0 + lrow) : min(m0 + lrow, n_nodes - 1);

  f32x4 acc[4];
#pragma unroll
  for (int i = 0; i < 4; ++i) acc[i] = (f32x4){0.f, 0.f, 0.f, 0.f};

#pragma unroll
  for (int ks = 0; ks < 4; ++ks) {
    const float4* xp =
        (const float4*)(x + (size_t)arow * F_IN + ks * 32 + lk * 8);
    const float4 q0 = xp[0];
    const float4 q1 = xp[1];
    const float fv[8] = {q0.x, q0.y, q0.z, q0.w, q1.x, q1.y, q1.z, q1.w};
    short8 ah;
#pragma unroll
    for (int i = 0; i < 8; ++i) ah[i] = (short)f2bf_rne(fv[i]);
#pragma unroll
    for (int nt = 0; nt < 4; ++nt) {
      const int n = nt * 16 + lrow;
      int off = (n << 8) + (ks * 64 + lk * 16);
      off ^= (n & 7) << 4;
      const short8 bh = *(const short8*)((const char*)wt_hi + off);
      acc[nt] = __builtin_amdgcn_mfma_f32_16x16x32_bf16(ah, bh, acc[nt], 0, 0, 0);
    }
  }

  // C/D: col = lane&15, row = (lane>>4)*4 + reg  [HW-verified]
#pragma unroll
  for (int nt = 0; nt < 4; ++nt) {
#pragma unroll
    for (int r = 0; r < 4; ++r) {
      const int row = m0 + lk * 4 + r;
      if (full || row < n_nodes)
        pre[(size_t)row * F_OUT + nt * 16 + lrow] = f2bf_rne(acc[nt][r]);
    }
  }
}

// ---------------------------------------------------------------------------
// Kernel B: out[r][f] = relu( sum_e val[e] * pre_bf16[col[e]][f] )
// (R6-exact, best measured.) One wave per row, half-wave per edge; per
// 16-edge group: 16 shuffle-pairs, then 8 independent gathers issued
// back-to-back, then 16 fmas on 4 accumulators. Padded slots v=0 gather
// row 0 (L1-hot). Fixed sum order -> deterministic.
// ---------------------------------------------------------------------------
__global__ __launch_bounds__(256) void gcn_spmm(
    const unsigned short* __restrict__ pre, const int* __restrict__ row_ptr,
    const int* __restrict__ edge_col, const float* __restrict__ edge_val,
    float* __restrict__ out, int n_nodes) {
  const int lane = threadIdx.x & 63;
  const int half = lane >> 5;
  const int fl = lane & 31;
  int row = (int)((blockIdx.x * blockDim.x + threadIdx.x) >> 6);
  row = __builtin_amdgcn_readfirstlane(row);
  if (row >= n_nodes) return;
  const int e0 = row_ptr[row];
  const int e1 = row_ptr[row + 1];

  float a0 = 0.f, a1 = 0.f, a2 = 0.f, a3 = 0.f;
  const char* prebase = (const char*)pre + ((size_t)fl << 2);  // fl-th uint

  for (int base = e0; base < e1; base += 64) {
    const int cnt = min(64, e1 - base);
    int myc = 0;
    float myv = 0.f;
    if (lane < cnt) {
      myc = edge_col[base + lane] << 7;  // byte offset of the row (64*2B)
      myv = edge_val[base + lane];
    }
    const int nb = (cnt + 15) >> 4;  // 16 edges per iteration
    for (int b = 0; b < nb; ++b) {
      const int j0 = b * 16;
      int   cc[8];
      float vv[8];
#pragma unroll
      for (int j = 0; j < 8; ++j) {
        const int idx = j0 + j * 2 + half;
        cc[j] = __shfl(myc, idx);
        vv[j] = __shfl(myv, idx);
      }
      unsigned int p[8];
#pragma unroll
      for (int j = 0; j < 8; ++j)
        p[j] = *(const unsigned int*)(prebase + (size_t)(unsigned int)cc[j]);
#pragma unroll
      for (int j = 0; j < 8; j += 2) {
        a0 = fmaf(vv[j], bf_lo(p[j]), a0);
        a1 = fmaf(vv[j], bf_hi(p[j]), a1);
        a2 = fmaf(vv[j + 1], bf_lo(p[j + 1]), a2);
        a3 = fmaf(vv[j + 1], bf_hi(p[j + 1]), a3);
      }
    }
  }

  // merge edge-parity halves: lanes l and l^32 hold the same feature pair
  float s0 = (a0 + a2) + __shfl_xor(a0 + a2, 32);
  float s1 = (a1 + a3) + __shfl_xor(a1 + a3, 32);
  if (half == 0) {
    float2 o = make_float2(fmaxf(s0, 0.f), fmaxf(s1, 0.f));
    *(float2*)(out + (size_t)row * F_OUT + fl * 2) = o;
  }
}

extern "C" void kernel_launch(void* const* d_in, const int* in_sizes, int n_in,
                              void* d_out, int out_size, void* d_ws, size_t ws_size,
                              hipStream_t stream) {
  const float* x        = (const float*)d_in[0];
  const float* w        = (const float*)d_in[1];
  const int*   edge_row = (const int*)d_in[2];
  const int*   edge_col = (const int*)d_in[3];
  const float* edge_val = (const float*)d_in[4];
  float* out = (float*)d_out;

  const int n_nodes = in_sizes[0] / F_IN;   // 50000
  const int n_edges = in_sizes[2];          // 800000

  unsigned short* pre = (unsigned short*)d_ws;  // n_nodes*64 bf16 = 6.4 MB
  int* row_ptr = (int*)((char*)d_ws +
                        (size_t)n_nodes * F_OUT * sizeof(unsigned short));

  const int m_tiles = (n_nodes + 15) / 16;
  const int gemm_blocks = (m_tiles + 3) / 4;
  const int rp_blocks = (n_nodes + 1 + 255) / 256;
  gcn_gemm_rowptr<<<gemm_blocks + rp_blocks, 256, 0, stream>>>(
      x, w, pre, edge_row, row_ptr, n_nodes, n_edges, gemm_blocks);

  const int spmm_blocks = ((size_t)n_nodes * 64 + 255) / 256;
  gcn_spmm<<<spmm_blocks, 256, 0, stream>>>(pre, row_ptr, edge_col, edge_val,
                                            out, n_nodes);
}